// Round 2
// baseline (226.054 us; speedup 1.0000x reference)
//
#include <hip/hip_runtime.h>

#define NN 8192      // nodes
#define NE 262144    // edges
#define FIN 512
#define HIDN 256
#define NC 16

// ---------------- degree / self-loop counting ----------------
// edge_index arrives as int32 (harness converts int64 -> int32), 2*NE elements.
__global__ __launch_bounds__(256) void deg_kernel(const int* __restrict__ ei,
                                                  int* __restrict__ cnt) {
    int e = blockIdx.x * 256 + threadIdx.x;
    int s = ei[e];
    int t = ei[NE + e];
    atomicAdd(&cnt[s], 1);
    if (s == t) atomicAdd(&cnt[NN + s], 1);
}

// w_i = relu(0.4 - (1+selfloops)/(1+outdeg))   [Wmat is diagonal: see analysis]
__global__ __launch_bounds__(256) void wdiag_kernel(const int* __restrict__ cnt,
                                                    float* __restrict__ wd) {
    int i = blockIdx.x * 256 + threadIdx.x;
    float deg = 1.0f + (float)cnt[i];
    float sl  = 1.0f + (float)cnt[NN + i];
    float u = 0.4f - sl / deg;
    wd[i] = u > 0.0f ? u : 0.0f;
}

// ---------------- fused GEMM + wd-scale + bias + relu + LayerNorm ----------------
// out[M,256] = LN(relu(wd[i] * (A[M,K] @ W[K,256]) + bias))
// block: 16 rows x 256 cols, 256 threads; thread: 4 rows x 4 cols.
// rg = wave id (rows rg*4..rg*4+3), cg = lane (cols cg*4..cg*4+3).
template<int K>
__global__ __launch_bounds__(256) void gemm_ln_kernel(
    const float* __restrict__ A, const float* __restrict__ W,
    const float* __restrict__ bias, const float* __restrict__ gam,
    const float* __restrict__ bet, const float* __restrict__ wd,
    float* __restrict__ out)
{
    __shared__ float lds[16 * 256];
    float4* lds4 = (float4*)lds;
    const int tid = threadIdx.x;
    const int block_row = blockIdx.x * 16;
    const int cg = tid & 63;
    const int rg = tid >> 6;

    float4 acc[4];
#pragma unroll
    for (int r = 0; r < 4; ++r) acc[r] = make_float4(0.f, 0.f, 0.f, 0.f);

    const float4* W4 = (const float4*)W;
    const float4* A4 = (const float4*)A;

    for (int k0 = 0; k0 < K; k0 += 256) {
        // stage A[block_row:+16, k0:k0+256] -> LDS (row-major 16 x 64 float4)
#pragma unroll
        for (int i = 0; i < 4; ++i) {
            int idx = tid + i * 256;            // 0..1023
            int r = idx >> 6, c4 = idx & 63;
            lds4[idx] = A4[(block_row + r) * (K / 4) + (k0 >> 2) + c4];
        }
        __syncthreads();
#pragma unroll 4
        for (int k4 = 0; k4 < 64; ++k4) {
            int k = k0 + k4 * 4;
            float4 w0 = W4[(k + 0) * 64 + cg];
            float4 w1 = W4[(k + 1) * 64 + cg];
            float4 w2 = W4[(k + 2) * 64 + cg];
            float4 w3 = W4[(k + 3) * 64 + cg];
#pragma unroll
            for (int r = 0; r < 4; ++r) {
                float4 a = lds4[(rg * 4 + r) * 64 + k4];   // wave-broadcast read
                acc[r].x = fmaf(a.x, w0.x, fmaf(a.y, w1.x, fmaf(a.z, w2.x, fmaf(a.w, w3.x, acc[r].x))));
                acc[r].y = fmaf(a.x, w0.y, fmaf(a.y, w1.y, fmaf(a.z, w2.y, fmaf(a.w, w3.y, acc[r].y))));
                acc[r].z = fmaf(a.x, w0.z, fmaf(a.y, w1.z, fmaf(a.z, w2.z, fmaf(a.w, w3.z, acc[r].z))));
                acc[r].w = fmaf(a.x, w0.w, fmaf(a.y, w1.w, fmaf(a.z, w2.w, fmaf(a.w, w3.w, acc[r].w))));
            }
        }
        __syncthreads();
    }

    // epilogue: scale + bias + relu, then LN per row via full-wave butterfly
    float4 bv  = ((const float4*)bias)[cg];
    float4 gv  = ((const float4*)gam)[cg];
    float4 btv = ((const float4*)bet)[cg];
#pragma unroll
    for (int r = 0; r < 4; ++r) {
        int row = block_row + rg * 4 + r;
        float wv = wd[row];
        float4 v;
        v.x = fmaxf(fmaf(wv, acc[r].x, bv.x), 0.f);
        v.y = fmaxf(fmaf(wv, acc[r].y, bv.y), 0.f);
        v.z = fmaxf(fmaf(wv, acc[r].z, bv.z), 0.f);
        v.w = fmaxf(fmaf(wv, acc[r].w, bv.w), 0.f);
        float s  = v.x + v.y + v.z + v.w;
        float ss = v.x * v.x + v.y * v.y + v.z * v.z + v.w * v.w;
#pragma unroll
        for (int off = 32; off >= 1; off >>= 1) {
            s  += __shfl_xor(s, off, 64);
            ss += __shfl_xor(ss, off, 64);
        }
        float mu  = s * (1.0f / 256.0f);
        float var = ss * (1.0f / 256.0f) - mu * mu;
        float rs  = rsqrtf(var + 1e-5f);
        float4 o;
        o.x = (v.x - mu) * rs * gv.x + btv.x;
        o.y = (v.y - mu) * rs * gv.y + btv.y;
        o.z = (v.z - mu) * rs * gv.z + btv.z;
        o.w = (v.w - mu) * rs * gv.w + btv.w;
        ((float4*)(out + row * 256))[cg] = o;
    }
}

// ---------------- head: emb = wd*(A@W2)+b2 ; out = [emb, log_softmax(emb)] ----------------
// block: 16 rows x 16 cols, thread = one output element.
__global__ __launch_bounds__(256) void out_kernel(
    const float* __restrict__ A, const float* __restrict__ W,
    const float* __restrict__ bias, const float* __restrict__ wd,
    float* __restrict__ out)
{
    __shared__ float sA[16 * 256];
    __shared__ float sW[256 * 16];
    const int tid = threadIdx.x;
    const int block_row = blockIdx.x * 16;
    const float4* A4 = (const float4*)(A + block_row * 256);
#pragma unroll
    for (int i = 0; i < 4; ++i) ((float4*)sA)[tid + i * 256] = A4[tid + i * 256];
#pragma unroll
    for (int i = 0; i < 4; ++i) ((float4*)sW)[tid + i * 256] = ((const float4*)W)[tid + i * 256];
    __syncthreads();

    const int row = tid >> 4;
    const int col = tid & 15;
    float acc = 0.f;
    const float4* sA4 = (const float4*)(sA + row * 256);
#pragma unroll 8
    for (int k4 = 0; k4 < 64; ++k4) {
        float4 a = sA4[k4];
        acc = fmaf(a.x, sW[(k4 * 4 + 0) * 16 + col], acc);
        acc = fmaf(a.y, sW[(k4 * 4 + 1) * 16 + col], acc);
        acc = fmaf(a.z, sW[(k4 * 4 + 2) * 16 + col], acc);
        acc = fmaf(a.w, sW[(k4 * 4 + 3) * 16 + col], acc);
    }
    float v = fmaf(wd[block_row + row], acc, bias[col]);

    // log-softmax over the 16 cols (lanes row*16..row*16+15 within the wave)
    float m = v;
#pragma unroll
    for (int off = 8; off >= 1; off >>= 1) m = fmaxf(m, __shfl_xor(m, off, 64));
    float e = __expf(v - m);
    float se = e;
#pragma unroll
    for (int off = 8; off >= 1; off >>= 1) se += __shfl_xor(se, off, 64);
    float lsm = (v - m) - __logf(se);

    int gi = (block_row + row) * 16 + col;
    out[gi] = v;
    out[NN * 16 + gi] = lsm;
}

// ---------------- launch ----------------
extern "C" void kernel_launch(void* const* d_in, const int* in_sizes, int n_in,
                              void* d_out, int out_size, void* d_ws, size_t ws_size,
                              hipStream_t stream) {
    const float* x      = (const float*)d_in[0];
    const int*   ei     = (const int*)d_in[1];     // int64 in reference -> int32 from harness
    const float* W0 = (const float*)d_in[2];
    const float* b0 = (const float*)d_in[3];
    const float* g0 = (const float*)d_in[4];
    const float* be0 = (const float*)d_in[5];
    const float* W1 = (const float*)d_in[6];
    const float* b1 = (const float*)d_in[7];
    const float* g1 = (const float*)d_in[8];
    const float* be1 = (const float*)d_in[9];
    const float* W2 = (const float*)d_in[10];
    const float* b2 = (const float*)d_in[11];
    float* out = (float*)d_out;

    char* ws = (char*)d_ws;
    int*   cnt = (int*)ws;                               // 2*NN ints  = 64 KB
    float* wd  = (float*)(ws + 64 * 1024);               // NN floats  = 32 KB
    float* h0  = (float*)(ws + 128 * 1024);              // NN*256 f32 = 8 MB
    float* h1  = (float*)(ws + 128 * 1024 + NN * 256 * 4);

    hipMemsetAsync(cnt, 0, 2 * NN * sizeof(int), stream);
    deg_kernel<<<NE / 256, 256, 0, stream>>>(ei, cnt);
    wdiag_kernel<<<NN / 256, 256, 0, stream>>>(cnt, wd);
    gemm_ln_kernel<FIN ><<<NN / 16, 256, 0, stream>>>(x,  W0, b0, g0, be0, wd, h0);
    gemm_ln_kernel<HIDN><<<NN / 16, 256, 0, stream>>>(h0, W1, b1, g1, be1, wd, h1);
    out_kernel<<<NN / 16, 256, 0, stream>>>(h1, W2, b2, wd, out);
}

// Round 3
// 123.310 us; speedup vs baseline: 1.8332x; 1.8332x over previous
//
#include <hip/hip_runtime.h>

#define NN 8192      // nodes
#define NE 262144    // edges
#define FIN 512
#define HIDN 256
#define NC 16

typedef __attribute__((ext_vector_type(8))) short bf16x8;   // MFMA A/B frag (4 VGPRs)
typedef __attribute__((ext_vector_type(4))) short bf16x4;
typedef __attribute__((ext_vector_type(4))) float f32x4;    // MFMA C/D frag

static __device__ __forceinline__ unsigned short f2bf(float f) {
    union { float f; unsigned u; } v; v.f = f;
    unsigned r = v.u + 0x7FFFu + ((v.u >> 16) & 1u);   // RNE
    return (unsigned short)(r >> 16);
}
static __device__ __forceinline__ float bf2f(unsigned short h) {
    union { unsigned u; float f; } v; v.u = ((unsigned)h) << 16;
    return v.f;
}

// ---------------- degree / self-loop counting ----------------
__global__ __launch_bounds__(256) void deg_kernel(const int* __restrict__ ei,
                                                  int* __restrict__ cnt) {
    int e = blockIdx.x * 256 + threadIdx.x;
    int s = ei[e];
    int t = ei[NE + e];
    atomicAdd(&cnt[s], 1);
    if (s == t) atomicAdd(&cnt[NN + s], 1);
}

// ---------------- prep: pack W0/W1 into bf16 MFMA B-fragment order + wd ----------------
// B frag layout for mfma_f32_16x16x32_bf16: lane holds B[k = (lane>>4)*8 + j][n = lane&15],
// j=0..7 contiguous. Packed: frag f = (nt*(K/32) + kc)*64 + lane, 8 bf16 each.
template<int K>
static __device__ __forceinline__ void pack_w(const float* __restrict__ W,
                                              unsigned short* __restrict__ Wp, int f) {
    constexpr int KC = K / 32;
    int lane = f & 63;
    int g = f >> 6;
    int kc = g % KC;
    int nt = g / KC;
    int n = nt * 16 + (lane & 15);
    int kbase = kc * 32 + (lane >> 4) * 8;
    bf16x8 v;
#pragma unroll
    for (int j = 0; j < 8; ++j) v[j] = (short)f2bf(W[(kbase + j) * 256 + n]);
    *(bf16x8*)&Wp[f * 8] = v;
}

__global__ __launch_bounds__(256) void prep_kernel(const int* __restrict__ cnt,
                                                   const float* __restrict__ W0,
                                                   const float* __restrict__ W1,
                                                   float* __restrict__ wd,
                                                   unsigned short* __restrict__ Wp0,
                                                   unsigned short* __restrict__ Wp1) {
    int b = blockIdx.x, tid = threadIdx.x;
    if (b < 64) {                      // W0: 16 nt * 16 kc * 64 = 16384 frags
        pack_w<512>(W0, Wp0, b * 256 + tid);
    } else if (b < 96) {               // W1: 16 nt * 8 kc * 64 = 8192 frags
        pack_w<256>(W1, Wp1, (b - 64) * 256 + tid);
    } else {                           // wd: w_i = relu(0.4 - (1+sl)/(1+deg))
        int i = (b - 96) * 256 + tid;
        float deg = 1.0f + (float)cnt[i];
        float sl  = 1.0f + (float)cnt[NN + i];
        float u = 0.4f - sl / deg;
        wd[i] = u > 0.0f ? u : 0.0f;
    }
}

// ---------------- MFMA GEMM + wd-scale + bias + relu + LayerNorm, bf16 out ----------------
// out[M,256] = LN(relu(wd[i]*(A[M,K]@W[K,256]) + bias)), stored bf16.
// Block: 32 rows x 256 cols, 256 threads (4 waves). Wave w: cols w*64..w*64+63,
// 2 m-tiles x 4 n-tiles of 16x16x32 MFMA. Grid = 8192/32 = 256 (1 block/CU).
template<int K, bool ABF>
__global__ __launch_bounds__(256) void gemm_mfma_ln(
    const void* __restrict__ Avoid, const unsigned short* __restrict__ Wp,
    const float* __restrict__ bias, const float* __restrict__ gam,
    const float* __restrict__ bet, const float* __restrict__ wd,
    unsigned short* __restrict__ outp)
{
    __shared__ unsigned short sA[32 * 136];   // 128-k chunk, row stride 136 (pad: 2-way banks)
    __shared__ float red[32][8];              // LN cross-wave partials: [row][wave*2 + {s,ss}]

    const int tid  = threadIdx.x;
    const int lane = tid & 63, wave = tid >> 6;
    const int quad = lane >> 4, l16 = lane & 15;
    const int row0 = blockIdx.x * 32;

    f32x4 acc[2][4];
#pragma unroll
    for (int mt = 0; mt < 2; ++mt)
#pragma unroll
        for (int nt = 0; nt < 4; ++nt) acc[mt][nt] = (f32x4){0.f, 0.f, 0.f, 0.f};

    const bf16x8* Wp8 = (const bf16x8*)Wp;

    for (int kb = 0; kb < K / 128; ++kb) {
        if (ABF) {   // A already bf16 (hidden activations)
            const bf16x8* A8 = (const bf16x8*)Avoid;
#pragma unroll
            for (int i = 0; i < 2; ++i) {
                int f = tid + i * 256;              // 0..511
                int r = f >> 4, c8 = f & 15;
                *(bf16x8*)&sA[r * 136 + c8 * 8] = A8[(row0 + r) * (K / 8) + kb * 16 + c8];
            }
        } else {     // A fp32 (input x): convert during staging
            const float4* A4 = (const float4*)Avoid;
#pragma unroll
            for (int i = 0; i < 4; ++i) {
                int f = tid + i * 256;              // 0..1023
                int r = f >> 5, c4 = f & 31;
                float4 v = A4[(row0 + r) * (K / 4) + kb * 32 + c4];
                bf16x4 h;
                h[0] = (short)f2bf(v.x); h[1] = (short)f2bf(v.y);
                h[2] = (short)f2bf(v.z); h[3] = (short)f2bf(v.w);
                *(bf16x4*)&sA[r * 136 + c4 * 4] = h;
            }
        }
        __syncthreads();
#pragma unroll
        for (int kc = 0; kc < 4; ++kc) {
            // A frag: A[m = l16][k = quad*8 + j], 16B contiguous ds_read_b128
            bf16x8 a0 = *(const bf16x8*)&sA[(l16)      * 136 + kc * 32 + quad * 8];
            bf16x8 a1 = *(const bf16x8*)&sA[(16 + l16) * 136 + kc * 32 + quad * 8];
#pragma unroll
            for (int nt = 0; nt < 4; ++nt) {
                bf16x8 b = Wp8[((wave * 4 + nt) * (K / 32) + kb * 4 + kc) * 64 + lane];
                acc[0][nt] = __builtin_amdgcn_mfma_f32_16x16x32_bf16(a0, b, acc[0][nt], 0, 0, 0);
                acc[1][nt] = __builtin_amdgcn_mfma_f32_16x16x32_bf16(a1, b, acc[1][nt], 0, 0, 0);
            }
        }
        __syncthreads();
    }

    // ---- epilogue: v = relu(wd*acc + bias); LN over 256 cols; store bf16 ----
    // C/D layout: col = l16 (within n-tile), row = quad*4 + reg (within m-tile).
    float bv[4], gv[4], btv[4];
#pragma unroll
    for (int nt = 0; nt < 4; ++nt) {
        int col = wave * 64 + nt * 16 + l16;
        bv[nt] = bias[col]; gv[nt] = gam[col]; btv[nt] = bet[col];
    }
    float vv[2][4][4];
    float s[2][4], ss[2][4];
#pragma unroll
    for (int mt = 0; mt < 2; ++mt)
#pragma unroll
        for (int reg = 0; reg < 4; ++reg) {
            float wdv = wd[row0 + mt * 16 + quad * 4 + reg];
            float ps = 0.f, pss = 0.f;
#pragma unroll
            for (int nt = 0; nt < 4; ++nt) {
                float v = fmaxf(fmaf(wdv, acc[mt][nt][reg], bv[nt]), 0.f);
                vv[mt][nt][reg] = v;
                ps += v; pss += v * v;
            }
            s[mt][reg] = ps; ss[mt][reg] = pss;
        }
    // reduce across the 16 lanes of each quad (covers this wave's 64 cols)
#pragma unroll
    for (int off = 1; off < 16; off <<= 1)
#pragma unroll
        for (int mt = 0; mt < 2; ++mt)
#pragma unroll
            for (int reg = 0; reg < 4; ++reg) {
                s[mt][reg]  += __shfl_xor(s[mt][reg],  off, 64);
                ss[mt][reg] += __shfl_xor(ss[mt][reg], off, 64);
            }
    if (l16 == 0) {
#pragma unroll
        for (int mt = 0; mt < 2; ++mt)
#pragma unroll
            for (int reg = 0; reg < 4; ++reg) {
                red[mt * 16 + quad * 4 + reg][wave * 2]     = s[mt][reg];
                red[mt * 16 + quad * 4 + reg][wave * 2 + 1] = ss[mt][reg];
            }
    }
    __syncthreads();
#pragma unroll
    for (int mt = 0; mt < 2; ++mt)
#pragma unroll
        for (int reg = 0; reg < 4; ++reg) {
            int rl = mt * 16 + quad * 4 + reg;
            float ts = red[rl][0] + red[rl][2] + red[rl][4] + red[rl][6];
            float tss = red[rl][1] + red[rl][3] + red[rl][5] + red[rl][7];
            float mu = ts * (1.0f / 256.0f);
            float var = tss * (1.0f / 256.0f) - mu * mu;
            float rs = rsqrtf(var + 1e-5f);
            int row = row0 + rl;
#pragma unroll
            for (int nt = 0; nt < 4; ++nt) {
                float o = (vv[mt][nt][reg] - mu) * rs * gv[nt] + btv[nt];
                outp[row * 256 + wave * 64 + nt * 16 + l16] = f2bf(o);
            }
        }
}

// ---------------- head: emb = wd*(A@W2)+b2 ; out = [emb, log_softmax(emb)] ----------------
__global__ __launch_bounds__(256) void out_kernel(
    const unsigned short* __restrict__ A, const float* __restrict__ W,
    const float* __restrict__ bias, const float* __restrict__ wd,
    float* __restrict__ out)
{
    __shared__ float sA[16 * 256];
    __shared__ float sW[256 * 16];
    const int tid = threadIdx.x;
    const int block_row = blockIdx.x * 16;
    const bf16x8* A8 = (const bf16x8*)(A + block_row * 256);
#pragma unroll
    for (int i = 0; i < 2; ++i) {
        int f = tid + i * 256;       // 0..511 frag of 8
        bf16x8 h = A8[f];
        float4 lo, hi;
        lo.x = bf2f((unsigned short)h[0]); lo.y = bf2f((unsigned short)h[1]);
        lo.z = bf2f((unsigned short)h[2]); lo.w = bf2f((unsigned short)h[3]);
        hi.x = bf2f((unsigned short)h[4]); hi.y = bf2f((unsigned short)h[5]);
        hi.z = bf2f((unsigned short)h[6]); hi.w = bf2f((unsigned short)h[7]);
        ((float4*)sA)[f * 2]     = lo;
        ((float4*)sA)[f * 2 + 1] = hi;
    }
#pragma unroll
    for (int i = 0; i < 4; ++i) ((float4*)sW)[tid + i * 256] = ((const float4*)W)[tid + i * 256];
    __syncthreads();

    const int row = tid >> 4;
    const int col = tid & 15;
    float acc = 0.f;
    const float4* sA4 = (const float4*)(sA + row * 256);
#pragma unroll 8
    for (int k4 = 0; k4 < 64; ++k4) {
        float4 a = sA4[k4];
        acc = fmaf(a.x, sW[(k4 * 4 + 0) * 16 + col], acc);
        acc = fmaf(a.y, sW[(k4 * 4 + 1) * 16 + col], acc);
        acc = fmaf(a.z, sW[(k4 * 4 + 2) * 16 + col], acc);
        acc = fmaf(a.w, sW[(k4 * 4 + 3) * 16 + col], acc);
    }
    float v = fmaf(wd[block_row + row], acc, bias[col]);

    float m = v;
#pragma unroll
    for (int off = 8; off >= 1; off >>= 1) m = fmaxf(m, __shfl_xor(m, off, 64));
    float e = __expf(v - m);
    float se = e;
#pragma unroll
    for (int off = 8; off >= 1; off >>= 1) se += __shfl_xor(se, off, 64);
    float lsm = (v - m) - __logf(se);

    int gi = (block_row + row) * 16 + col;
    out[gi] = v;
    out[NN * 16 + gi] = lsm;
}

// ---------------- launch ----------------
extern "C" void kernel_launch(void* const* d_in, const int* in_sizes, int n_in,
                              void* d_out, int out_size, void* d_ws, size_t ws_size,
                              hipStream_t stream) {
    const float* x  = (const float*)d_in[0];
    const int*   ei = (const int*)d_in[1];     // int64 in reference -> int32 from harness
    const float* W0 = (const float*)d_in[2];
    const float* b0 = (const float*)d_in[3];
    const float* g0 = (const float*)d_in[4];
    const float* be0 = (const float*)d_in[5];
    const float* W1 = (const float*)d_in[6];
    const float* b1 = (const float*)d_in[7];
    const float* g1 = (const float*)d_in[8];
    const float* be1 = (const float*)d_in[9];
    const float* W2 = (const float*)d_in[10];
    const float* b2 = (const float*)d_in[11];
    float* out = (float*)d_out;

    char* ws = (char*)d_ws;
    int*            cnt = (int*)ws;                                    // 64 KB
    float*          wd  = (float*)(ws + 64 * 1024);                    // 32 KB
    unsigned short* Wp0 = (unsigned short*)(ws + 96 * 1024);           // 256 KB
    unsigned short* Wp1 = (unsigned short*)(ws + 352 * 1024);          // 128 KB
    unsigned short* h0  = (unsigned short*)(ws + 480 * 1024);          // 4 MB
    unsigned short* h1  = (unsigned short*)(ws + 480 * 1024 + NN * 256 * 2);

    hipMemsetAsync(cnt, 0, 2 * NN * sizeof(int), stream);
    deg_kernel<<<NE / 256, 256, 0, stream>>>(ei, cnt);
    prep_kernel<<<128, 256, 0, stream>>>(cnt, W0, W1, wd, Wp0, Wp1);
    gemm_mfma_ln<FIN,  false><<<NN / 32, 256, 0, stream>>>(x,  Wp0, b0, g0, be0, wd, h0);
    gemm_mfma_ln<HIDN, true ><<<NN / 32, 256, 0, stream>>>(h0, Wp1, b1, g1, be1, wd, h1);
    out_kernel<<<NN / 16, 256, 0, stream>>>(h1, W2, b2, wd, out);
}

// Round 4
// 112.910 us; speedup vs baseline: 2.0021x; 1.0921x over previous
//
#include <hip/hip_runtime.h>

#define NN 8192      // nodes
#define NE 262144    // edges
#define FIN 512
#define HIDN 256
#define NC 16

typedef __attribute__((ext_vector_type(8))) short bf16x8;   // MFMA A/B frag (4 VGPRs)
typedef __attribute__((ext_vector_type(4))) short bf16x4;
typedef __attribute__((ext_vector_type(4))) float f32x4;    // MFMA C/D frag

static __device__ __forceinline__ unsigned short f2bf(float f) {
    union { float f; unsigned u; } v; v.f = f;
    unsigned r = v.u + 0x7FFFu + ((v.u >> 16) & 1u);   // RNE
    return (unsigned short)(r >> 16);
}

// ---------------- degree / self-loop counting (4 edges/thread) ----------------
__global__ __launch_bounds__(256) void deg_kernel(const int* __restrict__ ei,
                                                  int* __restrict__ cnt) {
    int e0 = (blockIdx.x * 256 + threadIdx.x) * 4;
    int4 s = *(const int4*)&ei[e0];
    int4 t = *(const int4*)&ei[NE + e0];
    atomicAdd(&cnt[s.x], 1);
    atomicAdd(&cnt[s.y], 1);
    atomicAdd(&cnt[s.z], 1);
    atomicAdd(&cnt[s.w], 1);
    if (s.x == t.x) atomicAdd(&cnt[NN + s.x], 1);
    if (s.y == t.y) atomicAdd(&cnt[NN + s.y], 1);
    if (s.z == t.z) atomicAdd(&cnt[NN + s.z], 1);
    if (s.w == t.w) atomicAdd(&cnt[NN + s.w], 1);
}

// ---------------- prep: pack W0/W1/W2 into bf16 B-frag order + wd ----------------
// B frag (mfma_f32_16x16x32_bf16): lane holds B[k=(lane>>4)*8+j][n=lane&15], j contiguous.
// frag index f = (nt*(K/32) + kc)*64 + lane.
template<int K, int N>
static __device__ __forceinline__ void pack_w(const float* __restrict__ W,
                                              unsigned short* __restrict__ Wp, int f) {
    constexpr int KC = K / 32;
    int lane = f & 63;
    int g = f >> 6;
    int kc = g % KC;
    int nt = g / KC;
    int n = nt * 16 + (lane & 15);
    int kbase = kc * 32 + (lane >> 4) * 8;
    bf16x8 v;
#pragma unroll
    for (int j = 0; j < 8; ++j) v[j] = (short)f2bf(W[(kbase + j) * N + n]);
    *(bf16x8*)&Wp[f * 8] = v;
}

__global__ __launch_bounds__(256) void prep_kernel(const int* __restrict__ cnt,
                                                   const float* __restrict__ W0,
                                                   const float* __restrict__ W1,
                                                   const float* __restrict__ W2,
                                                   float* __restrict__ wd,
                                                   unsigned short* __restrict__ Wp0,
                                                   unsigned short* __restrict__ Wp1,
                                                   unsigned short* __restrict__ Wp2) {
    int b = blockIdx.x, tid = threadIdx.x;
    if (b < 64) {                       // W0: 16*16*64 = 16384 frags
        pack_w<512, 256>(W0, Wp0, b * 256 + tid);
    } else if (b < 96) {                // W1: 16*8*64 = 8192 frags
        pack_w<256, 256>(W1, Wp1, (b - 64) * 256 + tid);
    } else if (b < 98) {                // W2: 1*8*64 = 512 frags
        pack_w<256, 16>(W2, Wp2, (b - 96) * 256 + tid);
    } else {                            // wd: relu(0.4 - (1+sl)/(1+deg))
        int i = (b - 98) * 256 + tid;
        float deg = 1.0f + (float)cnt[i];
        float sl  = 1.0f + (float)cnt[NN + i];
        float u = 0.4f - sl / deg;
        wd[i] = u > 0.0f ? u : 0.0f;
    }
}

// ---------------- LN epilogue: v=relu(wd*acc+bias); LN over 256 cols; bf16 -> sH ----------------
// Lane owns rows half*16+quad*4+reg (reg 0..3), cols wq*64+nt*16+l16 (nt 0..3).
static __device__ __forceinline__ void ln_epilogue(
    const f32x4 acc[4], const float* __restrict__ bias, const float* __restrict__ gam,
    const float* __restrict__ bet, const float wdr[4],
    int half, int wq, int quad, int l16,
    unsigned short* sH, float red[][8])
{
    float bv[4], gv[4], btv[4];
#pragma unroll
    for (int nt = 0; nt < 4; ++nt) {
        int col = wq * 64 + nt * 16 + l16;
        bv[nt] = bias[col]; gv[nt] = gam[col]; btv[nt] = bet[col];
    }
    float vv[4][4], s[4], ss[4];
#pragma unroll
    for (int reg = 0; reg < 4; ++reg) {
        float ps = 0.f, pss = 0.f;
#pragma unroll
        for (int nt = 0; nt < 4; ++nt) {
            float v = fmaxf(fmaf(wdr[reg], acc[nt][reg], bv[nt]), 0.f);
            vv[nt][reg] = v;
            ps += v; pss += v * v;
        }
        s[reg] = ps; ss[reg] = pss;
    }
#pragma unroll
    for (int off = 1; off < 16; off <<= 1)
#pragma unroll
        for (int reg = 0; reg < 4; ++reg) {
            s[reg]  += __shfl_xor(s[reg],  off, 64);
            ss[reg] += __shfl_xor(ss[reg], off, 64);
        }
    __syncthreads();                       // prior sH/red reads complete
    if (l16 == 0) {
#pragma unroll
        for (int reg = 0; reg < 4; ++reg) {
            int rl = half * 16 + quad * 4 + reg;
            red[rl][wq * 2]     = s[reg];
            red[rl][wq * 2 + 1] = ss[reg];
        }
    }
    __syncthreads();
#pragma unroll
    for (int reg = 0; reg < 4; ++reg) {
        int rl = half * 16 + quad * 4 + reg;
        float ts  = red[rl][0] + red[rl][2] + red[rl][4] + red[rl][6];
        float tss = red[rl][1] + red[rl][3] + red[rl][5] + red[rl][7];
        float mu  = ts * (1.0f / 256.0f);
        float var = tss * (1.0f / 256.0f) - mu * mu;
        float rs  = rsqrtf(var + 1e-5f);
#pragma unroll
        for (int nt = 0; nt < 4; ++nt) {
            float o = (vv[nt][reg] - mu) * rs * gv[nt] + btv[nt];
            sH[rl * 264 + wq * 64 + nt * 16 + l16] = f2bf(o);
        }
    }
    __syncthreads();                       // sH ready for next phase
}

// ---------------- mega: GEMM0+LN -> GEMM1+LN -> head + log_softmax ----------------
// Block = 32 rows, 512 threads (8 waves). wave: half = w>>2 (row half), wq = w&3 (col quarter).
// Grid 256 = 1 block/CU, 2 waves/SIMD.
__global__ __launch_bounds__(512) void mega_kernel(
    const float* __restrict__ x,
    const unsigned short* __restrict__ Wp0, const unsigned short* __restrict__ Wp1,
    const unsigned short* __restrict__ Wp2,
    const float* __restrict__ b0, const float* __restrict__ g0, const float* __restrict__ be0,
    const float* __restrict__ b1, const float* __restrict__ g1, const float* __restrict__ be1,
    const float* __restrict__ b2, const float* __restrict__ wd,
    float* __restrict__ out)
{
    __shared__ unsigned short sX[32 * 136];   // 128-k staging chunk (pad -> 2-way banks, free)
    __shared__ unsigned short sH[32 * 264];   // h tile (32 x 256 bf16, padded)
    __shared__ float red[32][8];

    const int tid  = threadIdx.x;
    const int lane = tid & 63, wave = tid >> 6;
    const int quad = lane >> 4, l16 = lane & 15;
    const int half = wave >> 2, wq = wave & 3;
    const int row0 = blockIdx.x * 32;

    float wdr[4];
#pragma unroll
    for (int reg = 0; reg < 4; ++reg) wdr[reg] = wd[row0 + half * 16 + quad * 4 + reg];

    const bf16x8* Wp0v = (const bf16x8*)Wp0;
    const bf16x8* Wp1v = (const bf16x8*)Wp1;
    const bf16x8* Wp2v = (const bf16x8*)Wp2;
    const float4* x4 = (const float4*)x;

    // ---- layer 0: h0 = LN(relu(wd * (x @ W0) + b0)) ----
    f32x4 acc[4];
#pragma unroll
    for (int nt = 0; nt < 4; ++nt) acc[nt] = (f32x4){0.f, 0.f, 0.f, 0.f};

    for (int kb = 0; kb < 4; ++kb) {
#pragma unroll
        for (int i = 0; i < 2; ++i) {
            int f = tid + i * 512;           // 0..1023
            int r = f >> 5, c4 = f & 31;
            float4 v = x4[(row0 + r) * 128 + kb * 32 + c4];
            bf16x4 h;
            h[0] = (short)f2bf(v.x); h[1] = (short)f2bf(v.y);
            h[2] = (short)f2bf(v.z); h[3] = (short)f2bf(v.w);
            *(bf16x4*)&sX[r * 136 + c4 * 4] = h;
        }
        __syncthreads();
#pragma unroll
        for (int kc = 0; kc < 4; ++kc) {
            bf16x8 a = *(const bf16x8*)&sX[(half * 16 + l16) * 136 + kc * 32 + quad * 8];
#pragma unroll
            for (int nt = 0; nt < 4; ++nt) {
                bf16x8 b = Wp0v[((wq * 4 + nt) * 16 + kb * 4 + kc) * 64 + lane];
                acc[nt] = __builtin_amdgcn_mfma_f32_16x16x32_bf16(a, b, acc[nt], 0, 0, 0);
            }
        }
        __syncthreads();
    }
    ln_epilogue(acc, b0, g0, be0, wdr, half, wq, quad, l16, sH, red);

    // ---- layer 1: h1 = LN(relu(wd * (h0 @ W1) + b1)), A from LDS ----
    f32x4 acc1[4];
#pragma unroll
    for (int nt = 0; nt < 4; ++nt) acc1[nt] = (f32x4){0.f, 0.f, 0.f, 0.f};
#pragma unroll
    for (int kc = 0; kc < 8; ++kc) {
        bf16x8 a = *(const bf16x8*)&sH[(half * 16 + l16) * 264 + kc * 32 + quad * 8];
#pragma unroll
        for (int nt = 0; nt < 4; ++nt) {
            bf16x8 b = Wp1v[((wq * 4 + nt) * 8 + kc) * 64 + lane];
            acc1[nt] = __builtin_amdgcn_mfma_f32_16x16x32_bf16(a, b, acc1[nt], 0, 0, 0);
        }
    }
    ln_epilogue(acc1, b1, g1, be1, wdr, half, wq, quad, l16, sH, red);

    // ---- head: emb = wd*(h1 @ W2) + b2 ; out = [emb, log_softmax(emb)] ----
    if (wq == 0) {   // waves 0 and 4 (one per row half)
        f32x4 acch = (f32x4){0.f, 0.f, 0.f, 0.f};
#pragma unroll
        for (int kc = 0; kc < 8; ++kc) {
            bf16x8 a = *(const bf16x8*)&sH[(half * 16 + l16) * 264 + kc * 32 + quad * 8];
            bf16x8 b = Wp2v[kc * 64 + lane];
            acch = __builtin_amdgcn_mfma_f32_16x16x32_bf16(a, b, acch, 0, 0, 0);
        }
        float bb = b2[l16];
#pragma unroll
        for (int reg = 0; reg < 4; ++reg) {
            int row = row0 + half * 16 + quad * 4 + reg;
            float v = fmaf(wdr[reg], acch[reg], bb);
            float m = v;
#pragma unroll
            for (int off = 8; off >= 1; off >>= 1) m = fmaxf(m, __shfl_xor(m, off, 64));
            float e = __expf(v - m);
            float se = e;
#pragma unroll
            for (int off = 8; off >= 1; off >>= 1) se += __shfl_xor(se, off, 64);
            float lsm = (v - m) - __logf(se);
            out[row * 16 + l16] = v;
            out[NN * 16 + row * 16 + l16] = lsm;
        }
    }
}

// ---------------- launch ----------------
extern "C" void kernel_launch(void* const* d_in, const int* in_sizes, int n_in,
                              void* d_out, int out_size, void* d_ws, size_t ws_size,
                              hipStream_t stream) {
    const float* x  = (const float*)d_in[0];
    const int*   ei = (const int*)d_in[1];     // int64 in reference -> int32 from harness
    const float* W0 = (const float*)d_in[2];
    const float* b0 = (const float*)d_in[3];
    const float* g0 = (const float*)d_in[4];
    const float* be0 = (const float*)d_in[5];
    const float* W1 = (const float*)d_in[6];
    const float* b1 = (const float*)d_in[7];
    const float* g1 = (const float*)d_in[8];
    const float* be1 = (const float*)d_in[9];
    const float* W2 = (const float*)d_in[10];
    const float* b2 = (const float*)d_in[11];
    float* out = (float*)d_out;

    char* ws = (char*)d_ws;
    int*            cnt = (int*)ws;                                    // 64 KB
    float*          wd  = (float*)(ws + 64 * 1024);                    // 32 KB
    unsigned short* Wp0 = (unsigned short*)(ws + 96 * 1024);           // 256 KB
    unsigned short* Wp1 = (unsigned short*)(ws + 352 * 1024);          // 128 KB
    unsigned short* Wp2 = (unsigned short*)(ws + 480 * 1024);          // 8 KB

    hipMemsetAsync(cnt, 0, 2 * NN * sizeof(int), stream);
    deg_kernel<<<NE / 1024, 256, 0, stream>>>(ei, cnt);
    prep_kernel<<<130, 256, 0, stream>>>(cnt, W0, W1, W2, wd, Wp0, Wp1, Wp2);
    mega_kernel<<<NN / 32, 512, 0, stream>>>(x, Wp0, Wp1, Wp2,
                                             b0, g0, be0, b1, g1, be1, b2, wd, out);
}